// Round 1
// baseline (995.320 us; speedup 1.0000x reference)
//
#include <hip/hip_runtime.h>
#include <math.h>

// GCN forward: 2x GCNConv (20->16->2) + ReLU + log_softmax
// N=100000 nodes, E=6400000 edges.
//
// Decomposition per layer (exact algebra of PyG GCNConv w/ self-loops):
//   y[i]   = (x[i] @ W) * dinv[i]
//   s[r]  += y[c]                (over directed edges r<-c)
//   out[i] = dinv[i]*(s[i] + y[i]) + b      (self-loop term = dinv^2 * xw[i])

#define XF 20
#define F1 16
#define F2 2

__global__ void deg_kernel(const int* __restrict__ rows, int E, int* __restrict__ deg) {
    int e = blockIdx.x * blockDim.x + threadIdx.x;
    if (e < E) atomicAdd(&deg[rows[e]], 1);
}

__global__ void dinv_kernel(const int* __restrict__ deg, float* __restrict__ dinv, int N) {
    int i = blockIdx.x * blockDim.x + threadIdx.x;
    if (i < N) dinv[i] = rsqrtf((float)deg[i] + 1.0f);  // +1 self-loop
}

// y1[i][j] = (sum_k x[i][k] * W1[k][j]) * dinv[i]
__global__ void xw1_kernel(const float* __restrict__ x, const float* __restrict__ W1,
                           const float* __restrict__ dinv, float* __restrict__ y1, int N) {
    __shared__ float Ws[XF * F1];
    for (int k = threadIdx.x; k < XF * F1; k += blockDim.x) Ws[k] = W1[k];
    __syncthreads();
    int i = blockIdx.x * blockDim.x + threadIdx.x;
    if (i >= N) return;
    // x row: 20 floats = 80 B, 16B-aligned -> 5x float4
    const float4* xv = (const float4*)(x + (size_t)i * XF);
    float xr[XF];
    #pragma unroll
    for (int q = 0; q < 5; q++) {
        float4 v = xv[q];
        xr[q*4+0] = v.x; xr[q*4+1] = v.y; xr[q*4+2] = v.z; xr[q*4+3] = v.w;
    }
    float d = dinv[i];
    float out[F1];
    #pragma unroll
    for (int j = 0; j < F1; j++) {
        float a = 0.f;
        #pragma unroll
        for (int k = 0; k < XF; k++) a += xr[k] * Ws[k * F1 + j];
        out[j] = a * d;
    }
    float4* o = (float4*)(y1 + (size_t)i * F1);
    o[0] = make_float4(out[0],  out[1],  out[2],  out[3]);
    o[1] = make_float4(out[4],  out[5],  out[6],  out[7]);
    o[2] = make_float4(out[8],  out[9],  out[10], out[11]);
    o[3] = make_float4(out[12], out[13], out[14], out[15]);
}

// s[r*16+j] += y[c*16+j], 16 lanes per edge
__global__ void scatter16_kernel(const int* __restrict__ rows, const int* __restrict__ cols,
                                 const float* __restrict__ y, float* __restrict__ s, int E) {
    long long gid = (long long)blockIdx.x * blockDim.x + threadIdx.x;
    int e = (int)(gid >> 4);
    if (e >= E) return;
    int j = (int)(gid & 15);
    int r = rows[e], c = cols[e];
    atomicAdd(&s[(size_t)r * F1 + j], y[(size_t)c * F1 + j]);
}

// h = relu(dinv[i]*(s1+y1) + b1[j])
__global__ void relu_kernel(const float* __restrict__ s1, const float* __restrict__ y1,
                            const float* __restrict__ dinv, const float* __restrict__ b1,
                            float* __restrict__ h, int N) {
    int idx = blockIdx.x * blockDim.x + threadIdx.x;
    if (idx >= N * F1) return;
    int i = idx >> 4, j = idx & 15;
    float v = dinv[i] * (s1[idx] + y1[idx]) + b1[j];
    h[idx] = v > 0.f ? v : 0.f;
}

// y2[i][j] = (sum_k h[i][k] * W2[k][j]) * dinv[i]
__global__ void hw2_kernel(const float* __restrict__ h, const float* __restrict__ W2,
                           const float* __restrict__ dinv, float* __restrict__ y2, int N) {
    __shared__ float Ws[F1 * F2];
    if (threadIdx.x < F1 * F2) Ws[threadIdx.x] = W2[threadIdx.x];
    __syncthreads();
    int i = blockIdx.x * blockDim.x + threadIdx.x;
    if (i >= N) return;
    const float4* hv = (const float4*)(h + (size_t)i * F1);
    float a0 = 0.f, a1 = 0.f;
    #pragma unroll
    for (int q = 0; q < 4; q++) {
        float4 v = hv[q];
        a0 += v.x * Ws[(q*4+0)*2] + v.y * Ws[(q*4+1)*2] + v.z * Ws[(q*4+2)*2] + v.w * Ws[(q*4+3)*2];
        a1 += v.x * Ws[(q*4+0)*2+1] + v.y * Ws[(q*4+1)*2+1] + v.z * Ws[(q*4+2)*2+1] + v.w * Ws[(q*4+3)*2+1];
    }
    float d = dinv[i];
    ((float2*)y2)[i] = make_float2(a0 * d, a1 * d);
}

// s2[r*2+j] += y2[c*2+j], 2 lanes per edge
__global__ void scatter2_kernel(const int* __restrict__ rows, const int* __restrict__ cols,
                                const float* __restrict__ y, float* __restrict__ s, int E) {
    long long gid = (long long)blockIdx.x * blockDim.x + threadIdx.x;
    int e = (int)(gid >> 1);
    if (e >= E) return;
    int j = (int)(gid & 1);
    int r = rows[e], c = cols[e];
    atomicAdd(&s[(size_t)r * F2 + j], y[(size_t)c * F2 + j]);
}

// v = dinv*(s2+y2)+b2; out = v - logsumexp(v)
__global__ void final_kernel(const float* __restrict__ s2, const float* __restrict__ y2,
                             const float* __restrict__ dinv, const float* __restrict__ b2,
                             float* __restrict__ out, int N) {
    int i = blockIdx.x * blockDim.x + threadIdx.x;
    if (i >= N) return;
    float d = dinv[i];
    float v0 = d * (s2[i*2]   + y2[i*2])   + b2[0];
    float v1 = d * (s2[i*2+1] + y2[i*2+1]) + b2[1];
    float m = fmaxf(v0, v1);
    float lse = m + logf(expf(v0 - m) + expf(v1 - m));
    ((float2*)out)[i] = make_float2(v0 - lse, v1 - lse);
}

extern "C" void kernel_launch(void* const* d_in, const int* in_sizes, int n_in,
                              void* d_out, int out_size, void* d_ws, size_t ws_size,
                              hipStream_t stream) {
    const float* x  = (const float*)d_in[0];
    const int*   ei = (const int*)d_in[1];
    const float* W1 = (const float*)d_in[2];
    const float* b1 = (const float*)d_in[3];
    const float* W2 = (const float*)d_in[4];
    const float* b2 = (const float*)d_in[5];
    float* out = (float*)d_out;

    const int N = in_sizes[0] / XF;
    const int E = in_sizes[1] / 2;
    const int* rows = ei;
    const int* cols = ei + E;

    // Workspace layout. Zero-region first (one memset): deg, s1, s2.
    char* ws = (char*)d_ws;
    size_t off = 0;
    int*   deg  = (int*)(ws + off);   off += (size_t)N * 4;
    float* s1   = (float*)(ws + off); off += (size_t)N * F1 * 4;
    float* s2   = (float*)(ws + off); off += (size_t)N * F2 * 4;
    size_t zero_bytes = off;
    float* dinv = (float*)(ws + off); off += (size_t)N * 4;
    float* y1   = (float*)(ws + off); off += (size_t)N * F1 * 4;
    float* h    = (float*)(ws + off); off += (size_t)N * F1 * 4;
    float* y2   = (float*)(ws + off); off += (size_t)N * F2 * 4;

    hipMemsetAsync(d_ws, 0, zero_bytes, stream);

    const int B = 256;
    deg_kernel<<<(E + B - 1) / B, B, 0, stream>>>(rows, E, deg);
    dinv_kernel<<<(N + B - 1) / B, B, 0, stream>>>(deg, dinv, N);
    xw1_kernel<<<(N + B - 1) / B, B, 0, stream>>>(x, W1, dinv, y1, N);
    {
        long long t = (long long)E * F1;
        scatter16_kernel<<<(int)((t + B - 1) / B), B, 0, stream>>>(rows, cols, y1, s1, E);
    }
    relu_kernel<<<(N * F1 + B - 1) / B, B, 0, stream>>>(s1, y1, dinv, b1, h, N);
    hw2_kernel<<<(N + B - 1) / B, B, 0, stream>>>(h, W2, dinv, y2, N);
    {
        long long t = (long long)E * F2;
        scatter2_kernel<<<(int)((t + B - 1) / B), B, 0, stream>>>(rows, cols, y2, s2, E);
    }
    final_kernel<<<(N + B - 1) / B, B, 0, stream>>>(s2, y2, dinv, b2, out, N);
}

// Round 2
// 854.263 us; speedup vs baseline: 1.1651x; 1.1651x over previous
//
#include <hip/hip_runtime.h>
#include <math.h>

// GCN forward: 2x GCNConv (20->16->2) + ReLU + log_softmax
// N=100000 nodes, E=6400000 edges.
//
// Per layer (exact algebra of PyG GCNConv w/ self-loops):
//   y[i]   = (x[i] @ W) * dinv[i]
//   s[i]   = sum_{c in in-neighbors(i)} y[c]        (pull-gather via CSR, NO atomics)
//   out[i] = dinv[i]*(s[i] + y[i]) + b              (self-loop = dinv^2 * xw)
//
// CSR built per-call via counting sort: histogram -> scan -> fill.

#define XF 20
#define F1 16
#define F2 2

__global__ void deg_kernel(const int* __restrict__ rows, int E, int* __restrict__ deg) {
    int e = blockIdx.x * blockDim.x + threadIdx.x;
    if (e < E) atomicAdd(&deg[rows[e]], 1);
}

// ---- 3-kernel exclusive scan over deg -> rowptr, plus dinv ----
__global__ void scan1_kernel(const int* __restrict__ deg, int* __restrict__ partials, int N) {
    __shared__ int tmp[256];
    int t = threadIdx.x;
    int i = blockIdx.x * 256 + t;
    tmp[t] = (i < N) ? deg[i] : 0;
    __syncthreads();
    for (int s = 128; s > 0; s >>= 1) {
        if (t < s) tmp[t] += tmp[t + s];
        __syncthreads();
    }
    if (t == 0) partials[blockIdx.x] = tmp[0];
}

__global__ void scan2_kernel(int* __restrict__ partials, int nb, int* __restrict__ rowptr,
                             int N, int E) {
    __shared__ int tmp[1024];
    int t = threadIdx.x;
    int v = (t < nb) ? partials[t] : 0;
    tmp[t] = v;
    __syncthreads();
    for (int d = 1; d < 1024; d <<= 1) {
        int u = (t >= d) ? tmp[t - d] : 0;
        __syncthreads();
        tmp[t] += u;
        __syncthreads();
    }
    if (t < nb) partials[t] = tmp[t] - v;  // exclusive
    if (t == 0) rowptr[N] = E;
}

__global__ void scan3_kernel(const int* __restrict__ deg, const int* __restrict__ partials,
                             int* __restrict__ rowptr, float* __restrict__ dinv, int N) {
    __shared__ int tmp[256];
    int t = threadIdx.x;
    int i = blockIdx.x * 256 + t;
    int v = (i < N) ? deg[i] : 0;
    tmp[t] = v;
    __syncthreads();
    for (int d = 1; d < 256; d <<= 1) {
        int u = (t >= d) ? tmp[t - d] : 0;
        __syncthreads();
        tmp[t] += u;
        __syncthreads();
    }
    if (i < N) {
        rowptr[i] = partials[blockIdx.x] + tmp[t] - v;     // exclusive scan
        dinv[i] = rsqrtf((float)v + 1.0f);                 // +1 self-loop
    }
}

__global__ void fill_kernel(const int* __restrict__ rows, const int* __restrict__ cols,
                            const int* __restrict__ rowptr, int* __restrict__ cur,
                            int* __restrict__ csr_col, int E) {
    int e = blockIdx.x * blockDim.x + threadIdx.x;
    if (e >= E) return;
    int r = rows[e];
    int slot = rowptr[r] + atomicAdd(&cur[r], 1);
    csr_col[slot] = cols[e];
}

// y1[i][j] = (sum_k x[i][k] * W1[k][j]) * dinv[i]
__global__ void xw1_kernel(const float* __restrict__ x, const float* __restrict__ W1,
                           const float* __restrict__ dinv, float* __restrict__ y1, int N) {
    __shared__ float Ws[XF * F1];
    for (int k = threadIdx.x; k < XF * F1; k += blockDim.x) Ws[k] = W1[k];
    __syncthreads();
    int i = blockIdx.x * blockDim.x + threadIdx.x;
    if (i >= N) return;
    const float4* xv = (const float4*)(x + (size_t)i * XF);
    float xr[XF];
    #pragma unroll
    for (int q = 0; q < 5; q++) {
        float4 v = xv[q];
        xr[q*4+0] = v.x; xr[q*4+1] = v.y; xr[q*4+2] = v.z; xr[q*4+3] = v.w;
    }
    float d = dinv[i];
    float out[F1];
    #pragma unroll
    for (int j = 0; j < F1; j++) {
        float a = 0.f;
        #pragma unroll
        for (int k = 0; k < XF; k++) a += xr[k] * Ws[k * F1 + j];
        out[j] = a * d;
    }
    float4* o = (float4*)(y1 + (size_t)i * F1);
    o[0] = make_float4(out[0],  out[1],  out[2],  out[3]);
    o[1] = make_float4(out[4],  out[5],  out[6],  out[7]);
    o[2] = make_float4(out[8],  out[9],  out[10], out[11]);
    o[3] = make_float4(out[12], out[13], out[14], out[15]);
}

// One wave per node: 16 lanes per edge (feature j), 4 edges in flight.
// h[i][j] = relu(dinv[i]*(sum_c y1[c][j] + y1[i][j]) + b1[j])
__global__ void gather16_kernel(const int* __restrict__ rowptr, const int* __restrict__ csr_col,
                                const float* __restrict__ y1, const float* __restrict__ dinv,
                                const float* __restrict__ b1, float* __restrict__ h, int N) {
    int wave = threadIdx.x >> 6;
    int lane = threadIdx.x & 63;
    int i = blockIdx.x * (blockDim.x >> 6) + wave;
    if (i >= N) return;
    int g = lane >> 4, j = lane & 15;
    int start = rowptr[i], end = rowptr[i + 1];
    float acc = 0.f;
    for (int slot = start + g; slot < end; slot += 4) {
        int c = csr_col[slot];
        acc += y1[(size_t)c * F1 + j];
    }
    acc += __shfl_xor(acc, 16);
    acc += __shfl_xor(acc, 32);
    if (lane < 16) {
        float v = dinv[i] * (acc + y1[(size_t)i * F1 + j]) + b1[j];
        h[(size_t)i * F1 + j] = v > 0.f ? v : 0.f;
    }
}

// y2[i][j] = (sum_k h[i][k] * W2[k][j]) * dinv[i]
__global__ void hw2_kernel(const float* __restrict__ h, const float* __restrict__ W2,
                           const float* __restrict__ dinv, float* __restrict__ y2, int N) {
    __shared__ float Ws[F1 * F2];
    if (threadIdx.x < F1 * F2) Ws[threadIdx.x] = W2[threadIdx.x];
    __syncthreads();
    int i = blockIdx.x * blockDim.x + threadIdx.x;
    if (i >= N) return;
    const float4* hv = (const float4*)(h + (size_t)i * F1);
    float a0 = 0.f, a1 = 0.f;
    #pragma unroll
    for (int q = 0; q < 4; q++) {
        float4 v = hv[q];
        a0 += v.x * Ws[(q*4+0)*2] + v.y * Ws[(q*4+1)*2] + v.z * Ws[(q*4+2)*2] + v.w * Ws[(q*4+3)*2];
        a1 += v.x * Ws[(q*4+0)*2+1] + v.y * Ws[(q*4+1)*2+1] + v.z * Ws[(q*4+2)*2+1] + v.w * Ws[(q*4+3)*2+1];
    }
    float d = dinv[i];
    ((float2*)y2)[i] = make_float2(a0 * d, a1 * d);
}

// One wave per node: each lane one edge (float2), full-wave reduce, fused log_softmax.
__global__ void gather2_kernel(const int* __restrict__ rowptr, const int* __restrict__ csr_col,
                               const float* __restrict__ y2, const float* __restrict__ dinv,
                               const float* __restrict__ b2, float* __restrict__ out, int N) {
    int wave = threadIdx.x >> 6;
    int lane = threadIdx.x & 63;
    int i = blockIdx.x * (blockDim.x >> 6) + wave;
    if (i >= N) return;
    int start = rowptr[i], end = rowptr[i + 1];
    float a0 = 0.f, a1 = 0.f;
    for (int slot = start + lane; slot < end; slot += 64) {
        int c = csr_col[slot];
        float2 v = ((const float2*)y2)[c];
        a0 += v.x;
        a1 += v.y;
    }
    #pragma unroll
    for (int m = 32; m > 0; m >>= 1) {
        a0 += __shfl_xor(a0, m);
        a1 += __shfl_xor(a1, m);
    }
    if (lane == 0) {
        float d = dinv[i];
        float2 yi = ((const float2*)y2)[i];
        float v0 = d * (a0 + yi.x) + b2[0];
        float v1 = d * (a1 + yi.y) + b2[1];
        float mm = fmaxf(v0, v1);
        float lse = mm + logf(expf(v0 - mm) + expf(v1 - mm));
        ((float2*)out)[i] = make_float2(v0 - lse, v1 - lse);
    }
}

static inline size_t align256(size_t x) { return (x + 255) & ~(size_t)255; }

extern "C" void kernel_launch(void* const* d_in, const int* in_sizes, int n_in,
                              void* d_out, int out_size, void* d_ws, size_t ws_size,
                              hipStream_t stream) {
    const float* x  = (const float*)d_in[0];
    const int*   ei = (const int*)d_in[1];
    const float* W1 = (const float*)d_in[2];
    const float* b1 = (const float*)d_in[3];
    const float* W2 = (const float*)d_in[4];
    const float* b2 = (const float*)d_in[5];
    float* out = (float*)d_out;

    const int N = in_sizes[0] / XF;
    const int E = in_sizes[1] / 2;
    const int* rows = ei;
    const int* cols = ei + E;

    // Workspace layout; zero-region first (deg + cur), one memset.
    char* ws = (char*)d_ws;
    size_t off = 0;
    int*   deg     = (int*)(ws + off);   off = align256(off + (size_t)N * 4);
    int*   cur     = (int*)(ws + off);   off = align256(off + (size_t)N * 4);
    size_t zero_bytes = off;
    int*   rowptr  = (int*)(ws + off);   off = align256(off + (size_t)(N + 1) * 4);
    int*   parts   = (int*)(ws + off);   off = align256(off + 1024 * 4);
    int*   csr_col = (int*)(ws + off);   off = align256(off + (size_t)E * 4);
    float* dinv    = (float*)(ws + off); off = align256(off + (size_t)N * 4);
    float* y1      = (float*)(ws + off); off = align256(off + (size_t)N * F1 * 4);
    float* h       = (float*)(ws + off); off = align256(off + (size_t)N * F1 * 4);
    float* y2      = (float*)(ws + off); off = align256(off + (size_t)N * F2 * 4);

    hipMemsetAsync(d_ws, 0, zero_bytes, stream);

    const int B = 256;
    const int nbN = (N + B - 1) / B;   // 391
    const int nbE = (E + B - 1) / B;   // 25000

    deg_kernel<<<nbE, B, 0, stream>>>(rows, E, deg);
    scan1_kernel<<<nbN, B, 0, stream>>>(deg, parts, N);
    scan2_kernel<<<1, 1024, 0, stream>>>(parts, nbN, rowptr, N, E);
    scan3_kernel<<<nbN, B, 0, stream>>>(deg, parts, rowptr, dinv, N);
    fill_kernel<<<nbE, B, 0, stream>>>(rows, cols, rowptr, cur, csr_col, E);
    xw1_kernel<<<nbN, B, 0, stream>>>(x, W1, dinv, y1, N);
    gather16_kernel<<<(N + 3) / 4, B, 0, stream>>>(rowptr, csr_col, y1, dinv, b1, h, N);
    hw2_kernel<<<nbN, B, 0, stream>>>(h, W2, dinv, y2, N);
    gather2_kernel<<<(N + 3) / 4, B, 0, stream>>>(rowptr, csr_col, y2, dinv, b2, out, N);
}